// Round 1
// baseline (464.046 us; speedup 1.0000x reference)
//
#include <hip/hip_runtime.h>
#include <math.h>

#define NTOK 1024
#define QDIM 512
#define NH 8
#define DHD 64
#define ATT_SCALE 0.125f

// Layouts: q_t/k_t/v_t/o_t are (B*H, N, DH) fp32.

// ---------------- QKV projection: C[row,c] = sum_d x[row,d]*W[c,d] ----------------
__global__ __launch_bounds__(256) void proj_qkv_kernel(
    const float* __restrict__ x,
    const float* __restrict__ Wq, const float* __restrict__ Wk, const float* __restrict__ Wv,
    float* __restrict__ q_t, float* __restrict__ k_t, float* __restrict__ v_t)
{
  const float* W = (blockIdx.z == 0) ? Wq : (blockIdx.z == 1) ? Wk : Wv;
  float* dst = (blockIdx.z == 0) ? q_t : (blockIdx.z == 1) ? k_t : v_t;
  const int h = blockIdx.x;          // 64-col tile == one head
  const int rowt = blockIdx.y;       // 0..31
  const int row0 = rowt * 64;
  const int b = rowt >> 4;
  const int iloc0 = (rowt & 15) * 64;

  __shared__ float As[16][68];   // [kk][row]
  __shared__ float Bs[16][68];   // [kk][col]

  const int t = threadIdx.x;
  const int lr = t >> 2;             // 0..63
  const int lk = t & 3;              // float4 chunk in k-slab of 16
  const int ra0 = (t >> 4) * 4;
  const int ca0 = (t & 15) * 4;

  float acc[4][4] = {{0.f}};

  const float* ax = &x[(size_t)(row0 + lr) * QDIM + lk * 4];
  const float* aw = &W[(size_t)(h * 64 + lr) * QDIM + lk * 4];

  for (int kt = 0; kt < 32; ++kt) {
    float4 av = *(const float4*)&ax[kt * 16];
    float4 bv = *(const float4*)&aw[kt * 16];
    __syncthreads();
    As[lk*4+0][lr] = av.x; As[lk*4+1][lr] = av.y; As[lk*4+2][lr] = av.z; As[lk*4+3][lr] = av.w;
    Bs[lk*4+0][lr] = bv.x; Bs[lk*4+1][lr] = bv.y; Bs[lk*4+2][lr] = bv.z; Bs[lk*4+3][lr] = bv.w;
    __syncthreads();
#pragma unroll
    for (int kk = 0; kk < 16; ++kk) {
      float4 a4 = *(const float4*)&As[kk][ra0];
      float4 b4 = *(const float4*)&Bs[kk][ca0];
      const float aa[4] = {a4.x, a4.y, a4.z, a4.w};
      const float bb[4] = {b4.x, b4.y, b4.z, b4.w};
#pragma unroll
      for (int i = 0; i < 4; ++i)
#pragma unroll
        for (int j = 0; j < 4; ++j)
          acc[i][j] += aa[i] * bb[j];
    }
  }

  float* dbase = &dst[((size_t)((b * NH + h) * NTOK) + iloc0) * DHD];
#pragma unroll
  for (int rr = 0; rr < 4; ++rr) {
    float4 o = make_float4(acc[rr][0], acc[rr][1], acc[rr][2], acc[rr][3]);
    *(float4*)&dbase[(size_t)(ra0 + rr) * DHD + ca0] = o;
  }
}

// ---------------- mask resize + count ----------------
__global__ void mask_cnt_kernel(const float* __restrict__ mask,
                                float* __restrict__ m_ws, float* __restrict__ cnt_ws)
{
  const int t = threadIdx.x;           // 0..1023
  const int r = t >> 5, c = t & 31;
  const float v = mask[(2 * r) * 64 + 2 * c];
  m_ws[t] = v;
  __shared__ float red[1024];
  red[t] = v;
  __syncthreads();
  for (int s = 512; s > 0; s >>= 1) {
    if (t < s) red[t] += red[t + s];
    __syncthreads();
  }
  if (t == 0) cnt_ws[0] = red[0];
}

// ---------------- AdaIN on batch-1 k/v, in place ----------------
__global__ __launch_bounds__(256) void adain_kernel(
    float* __restrict__ k_t, float* __restrict__ v_t,
    const float* __restrict__ m, const float* __restrict__ cnt_ws)
{
  float* arr = (blockIdx.y == 0) ? k_t : v_t;
  const int h = blockIdx.x;
  float* refp  = arr + (size_t)(0 * NH + h) * NTOK * DHD;
  float* featp = arr + (size_t)(1 * NH + h) * NTOK * DHD;

  const int t = threadIdx.x;
  const int dh = t & 63;
  const int ig = t >> 6;   // 0..3

  float rs = 0.f, rq = 0.f, fs = 0.f, fq = 0.f;
  for (int i = ig; i < NTOK; i += 4) {
    const float rv = refp[(size_t)i * DHD + dh];
    rs += rv; rq += rv * rv;
    const float fv = featp[(size_t)i * DHD + dh];
    const float mm = m[i];
    fs += mm * fv; fq += mm * fv * fv;
  }

  __shared__ float red[4][260];
  red[0][t] = rs; red[1][t] = rq; red[2][t] = fs; red[3][t] = fq;
  __syncthreads();

  __shared__ float sA[64], sB[64];
  if (ig == 0) {
    rs = red[0][dh] + red[0][dh + 64] + red[0][dh + 128] + red[0][dh + 192];
    rq = red[1][dh] + red[1][dh + 64] + red[1][dh + 128] + red[1][dh + 192];
    fs = red[2][dh] + red[2][dh + 64] + red[2][dh + 128] + red[2][dh + 192];
    fq = red[3][dh] + red[3][dh + 64] + red[3][dh + 128] + red[3][dh + 192];
    const float cnt = cnt_ws[0];
    const float rmean = rs * (1.0f / 1024.0f);
    const float rvar = (rq - 1024.0f * rmean * rmean) * (1.0f / 1023.0f);
    const float rstd = sqrtf(fmaxf(rvar, 0.f));
    const float fmean = fs / cnt;
    const float fvar = (fq - cnt * fmean * fmean) / (cnt - 1.0f);
    const float fstd = sqrtf(fmaxf(fvar, 0.f));
    const float sc = rstd / fstd;
    sA[dh] = sc;
    sB[dh] = rmean - fmean * sc;
  }
  __syncthreads();

  const float a = sA[dh], bsh = sB[dh];
  for (int i = ig; i < NTOK; i += 4) {
    const float fv = featp[(size_t)i * DHD + dh];
    const float nv = fv * a + bsh;
    featp[(size_t)i * DHD + dh] = (m[i] != 0.f) ? nv : fv;
  }
}

// ---------------- flash attention, KV len 2048 via indexing ----------------
__global__ __launch_bounds__(256) void attn_kernel(
    const float* __restrict__ q_t, const float* __restrict__ k_t, const float* __restrict__ v_t,
    const float* __restrict__ m_ws, float* __restrict__ o_t)
{
  const int bh = blockIdx.y;
  const int b = bh >> 3;
  const int h = bh & 7;
  const int i0 = blockIdx.x * 32;

  const float* qh   = q_t + (size_t)bh * NTOK * DHD;
  const float* kown = k_t + (size_t)bh * NTOK * DHD;
  const float* kref = k_t + (size_t)h  * NTOK * DHD;
  const float* vown = v_t + (size_t)bh * NTOK * DHD;
  const float* vref = v_t + (size_t)h  * NTOK * DHD;

  __shared__ float Qt[64][34];   // [d][r], pre-scaled
  __shared__ float Kt[64][68];   // [d][j]
  __shared__ float Pt[64][34];   // [j][r]
  __shared__ float Vt[64][68];   // [j][d]

  const int t = threadIdx.x;

  {
    const int r = t >> 3;
    const int dq = t & 7;
    const float* src = &qh[(size_t)(i0 + r) * DHD + dq * 8];
    float4 a = *(const float4*)&src[0];
    float4 c = *(const float4*)&src[4];
    const int d0 = dq * 8;
    Qt[d0+0][r] = a.x * ATT_SCALE; Qt[d0+1][r] = a.y * ATT_SCALE;
    Qt[d0+2][r] = a.z * ATT_SCALE; Qt[d0+3][r] = a.w * ATT_SCALE;
    Qt[d0+4][r] = c.x * ATT_SCALE; Qt[d0+5][r] = c.y * ATT_SCALE;
    Qt[d0+6][r] = c.z * ATT_SCALE; Qt[d0+7][r] = c.w * ATT_SCALE;
  }

  const int rg = t >> 4;       // 0..15
  const int cg = t & 15;       // 0..15
  const int r0 = rg * 2;
  const int c0 = cg * 4;

  float mneg[2];
#pragma unroll
  for (int rr = 0; rr < 2; ++rr)
    mneg[rr] = (b == 1) ? (1.0f - m_ws[i0 + r0 + rr]) * (-1e9f) : 0.0f;

  float mrow[2] = {-1e30f, -1e30f};
  float lrow[2] = {0.f, 0.f};
  float acc[2][4] = {{0.f}};

  const int lj = t >> 2;       // 0..63
  const int lq = t & 3;

  for (int kt = 0; kt < 32; ++kt) {
    const int jsrc = kt * 64 + lj;
    const float* ksrc;
    const float* vsrc;
    if (jsrc < NTOK) { ksrc = &kown[(size_t)jsrc * DHD]; vsrc = &vown[(size_t)jsrc * DHD]; }
    else             { ksrc = &kref[(size_t)(jsrc - NTOK) * DHD]; vsrc = &vref[(size_t)(jsrc - NTOK) * DHD]; }

    __syncthreads();   // previous iteration's reads of Kt/Vt/Pt done
#pragma unroll
    for (int u = 0; u < 4; ++u) {
      const int d0 = lq * 16 + u * 4;
      float4 kk4 = *(const float4*)&ksrc[d0];
      Kt[d0+0][lj] = kk4.x; Kt[d0+1][lj] = kk4.y; Kt[d0+2][lj] = kk4.z; Kt[d0+3][lj] = kk4.w;
      float4 vv4 = *(const float4*)&vsrc[d0];
      *(float4*)&Vt[lj][d0] = vv4;
    }
    __syncthreads();

    float s[2][4] = {{0.f}};
#pragma unroll
    for (int d = 0; d < 64; ++d) {
      float2 qq = *(const float2*)&Qt[d][r0];
      float4 kk = *(const float4*)&Kt[d][c0];
      s[0][0] += qq.x * kk.x; s[0][1] += qq.x * kk.y; s[0][2] += qq.x * kk.z; s[0][3] += qq.x * kk.w;
      s[1][0] += qq.y * kk.x; s[1][1] += qq.y * kk.y; s[1][2] += qq.y * kk.z; s[1][3] += qq.y * kk.w;
    }
    if (kt >= 16) {
#pragma unroll
      for (int rr = 0; rr < 2; ++rr) {
        s[rr][0] += mneg[rr]; s[rr][1] += mneg[rr];
        s[rr][2] += mneg[rr]; s[rr][3] += mneg[rr];
      }
    }

#pragma unroll
    for (int rr = 0; rr < 2; ++rr) {
      float tm = fmaxf(fmaxf(s[rr][0], s[rr][1]), fmaxf(s[rr][2], s[rr][3]));
#pragma unroll
      for (int off = 1; off < 16; off <<= 1)
        tm = fmaxf(tm, __shfl_xor(tm, off, 16));
      const float mn = fmaxf(mrow[rr], tm);
      const float al = __expf(mrow[rr] - mn);
      mrow[rr] = mn;
      const float p0 = __expf(s[rr][0] - mn);
      const float p1 = __expf(s[rr][1] - mn);
      const float p2 = __expf(s[rr][2] - mn);
      const float p3 = __expf(s[rr][3] - mn);
      float ps = p0 + p1 + p2 + p3;
#pragma unroll
      for (int off = 1; off < 16; off <<= 1)
        ps += __shfl_xor(ps, off, 16);
      lrow[rr] = lrow[rr] * al + ps;
      acc[rr][0] *= al; acc[rr][1] *= al; acc[rr][2] *= al; acc[rr][3] *= al;
      Pt[c0+0][r0+rr] = p0; Pt[c0+1][r0+rr] = p1;
      Pt[c0+2][r0+rr] = p2; Pt[c0+3][r0+rr] = p3;
    }
    __syncthreads();

#pragma unroll
    for (int j = 0; j < 64; ++j) {
      float2 pp = *(const float2*)&Pt[j][r0];
      float4 vv = *(const float4*)&Vt[j][c0];
      acc[0][0] += pp.x * vv.x; acc[0][1] += pp.x * vv.y; acc[0][2] += pp.x * vv.z; acc[0][3] += pp.x * vv.w;
      acc[1][0] += pp.y * vv.x; acc[1][1] += pp.y * vv.y; acc[1][2] += pp.y * vv.z; acc[1][3] += pp.y * vv.w;
    }
  }

  float* ob = &o_t[((size_t)bh * NTOK + i0) * DHD];
#pragma unroll
  for (int rr = 0; rr < 2; ++rr) {
    const float inv = 1.0f / lrow[rr];
    float4 o = make_float4(acc[rr][0]*inv, acc[rr][1]*inv, acc[rr][2]*inv, acc[rr][3]*inv);
    *(float4*)&ob[(size_t)(r0 + rr) * DHD + c0] = o;
  }
}

// ---------------- output projection + bias ----------------
__global__ __launch_bounds__(256) void out_proj_kernel(
    const float* __restrict__ o_t, const float* __restrict__ Wo,
    const float* __restrict__ bo, float* __restrict__ out)
{
  const int ct = blockIdx.x;       // output-channel tile (0..7)
  const int rowt = blockIdx.y;     // 0..31
  const int row0 = rowt * 64;
  const int b = rowt >> 4;
  const int iloc0 = (rowt & 15) * 64;
  const int c0 = ct * 64;

  __shared__ float As[16][68];
  __shared__ float Bs[16][68];

  const int t = threadIdx.x;
  const int lr = t >> 2;
  const int lk = t & 3;
  const int ra0 = (t >> 4) * 4;
  const int ca0 = (t & 15) * 4;

  float acc[4][4] = {{0.f}};

  for (int kt = 0; kt < 32; ++kt) {
    const int head = kt >> 2;
    const int coff = (kt & 3) * 16 + lk * 4;
    float4 av = *(const float4*)&o_t[((size_t)((b * NH + head) * NTOK) + iloc0 + lr) * DHD + coff];
    float4 bv = *(const float4*)&Wo[(size_t)(c0 + lr) * QDIM + kt * 16 + lk * 4];
    __syncthreads();
    As[lk*4+0][lr] = av.x; As[lk*4+1][lr] = av.y; As[lk*4+2][lr] = av.z; As[lk*4+3][lr] = av.w;
    Bs[lk*4+0][lr] = bv.x; Bs[lk*4+1][lr] = bv.y; Bs[lk*4+2][lr] = bv.z; Bs[lk*4+3][lr] = bv.w;
    __syncthreads();
#pragma unroll
    for (int kk = 0; kk < 16; ++kk) {
      float4 a4 = *(const float4*)&As[kk][ra0];
      float4 b4 = *(const float4*)&Bs[kk][ca0];
      const float aa[4] = {a4.x, a4.y, a4.z, a4.w};
      const float bb[4] = {b4.x, b4.y, b4.z, b4.w};
#pragma unroll
      for (int i = 0; i < 4; ++i)
#pragma unroll
        for (int j = 0; j < 4; ++j)
          acc[i][j] += aa[i] * bb[j];
    }
  }

#pragma unroll
  for (int rr = 0; rr < 4; ++rr) {
    float4 o;
    o.x = acc[rr][0] + bo[c0 + ca0 + 0];
    o.y = acc[rr][1] + bo[c0 + ca0 + 1];
    o.z = acc[rr][2] + bo[c0 + ca0 + 2];
    o.w = acc[rr][3] + bo[c0 + ca0 + 3];
    *(float4*)&out[(size_t)(row0 + ra0 + rr) * QDIM + c0 + ca0] = o;
  }
}

extern "C" void kernel_launch(void* const* d_in, const int* in_sizes, int n_in,
                              void* d_out, int out_size, void* d_ws, size_t ws_size,
                              hipStream_t stream) {
  const float* x    = (const float*)d_in[0];
  const float* mask = (const float*)d_in[1];
  const float* Wq   = (const float*)d_in[2];
  const float* Wk   = (const float*)d_in[3];
  const float* Wv   = (const float*)d_in[4];
  const float* Wo   = (const float*)d_in[5];
  const float* bo   = (const float*)d_in[6];
  float* out = (float*)d_out;

  float* q_t  = (float*)d_ws;                       // 16*1024*64
  float* k_t  = q_t + (size_t)16 * NTOK * DHD;
  float* v_t  = k_t + (size_t)16 * NTOK * DHD;
  float* o_t  = v_t + (size_t)16 * NTOK * DHD;
  float* m_ws = o_t + (size_t)16 * NTOK * DHD;      // 1024
  float* cnt_ws = m_ws + NTOK;                      // 1

  proj_qkv_kernel<<<dim3(8, 32, 3), 256, 0, stream>>>(x, Wq, Wk, Wv, q_t, k_t, v_t);
  mask_cnt_kernel<<<1, 1024, 0, stream>>>(mask, m_ws, cnt_ws);
  adain_kernel<<<dim3(8, 2), 256, 0, stream>>>(k_t, v_t, m_ws, cnt_ws);
  attn_kernel<<<dim3(32, 16), 256, 0, stream>>>(q_t, k_t, v_t, m_ws, o_t);
  out_proj_kernel<<<dim3(8, 32), 256, 0, stream>>>(o_t, Wo, bo, out);
}

// Round 2
// 184.963 us; speedup vs baseline: 2.5089x; 2.5089x over previous
//
#include <hip/hip_runtime.h>
#include <math.h>

#define NTOK 1024
#define QDIM 512
#define NH 8
#define DHD 64

using s16x8 = __attribute__((ext_vector_type(8))) short;
using f32x4 = __attribute__((ext_vector_type(4))) float;

__device__ __forceinline__ unsigned short f2bf(float x) {
  union { float f; unsigned u; } v; v.f = x;
  unsigned r = (v.u + 0x7fffu + ((v.u >> 16) & 1u)) >> 16;
  return (unsigned short)r;
}
__device__ __forceinline__ float bf2f(unsigned short h) {
  union { unsigned u; float f; } v; v.u = ((unsigned)h) << 16;
  return v.f;
}

// ---------------- cast x + weights to bf16 (contiguous dst) ----------------
__global__ __launch_bounds__(256) void cast_kernel(
    const float* __restrict__ x, const float* __restrict__ Wq, const float* __restrict__ Wk,
    const float* __restrict__ Wv, const float* __restrict__ Wo, unsigned short* __restrict__ dst)
{
  const int tid = blockIdx.x * 256 + threadIdx.x;   // 524288 threads
  const int e = tid * 4;
  const float* src;
  if (e < 1048576) {
    src = x + e;
  } else {
    const int we = e - 1048576;
    const int wi = we >> 18;          // 0..3
    const int off = we & 262143;
    src = (wi == 0 ? Wq : wi == 1 ? Wk : wi == 2 ? Wv : Wo) + off;
  }
  float4 v = *(const float4*)src;
  ushort4 o;
  o.x = f2bf(v.x); o.y = f2bf(v.y); o.z = f2bf(v.z); o.w = f2bf(v.w);
  *(ushort4*)&dst[e] = o;
}

// ---------------- mask resize + count ----------------
__global__ void mask_cnt_kernel(const float* __restrict__ mask,
                                float* __restrict__ m_ws, float* __restrict__ cnt_ws)
{
  const int t = threadIdx.x;           // 0..1023
  const int r = t >> 5, c = t & 31;
  const float v = mask[(2 * r) * 64 + 2 * c];
  m_ws[t] = v;
  __shared__ float red[1024];
  red[t] = v;
  __syncthreads();
  for (int s = 512; s > 0; s >>= 1) {
    if (t < s) red[t] += red[t + s];
    __syncthreads();
  }
  if (t == 0) cnt_ws[0] = red[0];
}

// ---------------- QKV projection (MFMA): q/k/v bf16, q pre-scaled ----------------
__global__ __launch_bounds__(256) void proj_mfma_kernel(
    const unsigned short* __restrict__ x_b, const unsigned short* __restrict__ w_b,
    unsigned short* __restrict__ q_b, unsigned short* __restrict__ k_b, unsigned short* __restrict__ v_b)
{
  const int w = threadIdx.x >> 6;
  const int l = threadIdx.x & 63;
  const int lq = l & 15, lg = l >> 4;
  const int tile = blockIdx.x * 4 + w;          // 0..127 (16-token tiles)
  const int mat = blockIdx.y >> 3;              // 0:q 1:k 2:v
  const int h = blockIdx.y & 7;
  const unsigned short* W = w_b + (size_t)mat * 262144 + (size_t)(h * 64) * QDIM;
  const int tok0 = tile * 16;

  f32x4 acc[4] = {};
  for (int kt = 0; kt < 16; ++kt) {
    s16x8 a = *(const s16x8*)&x_b[(size_t)(tok0 + lq) * QDIM + kt * 32 + lg * 8];
#pragma unroll
    for (int nf = 0; nf < 4; ++nf) {
      s16x8 bfr = *(const s16x8*)&W[(size_t)(nf * 16 + lq) * QDIM + kt * 32 + lg * 8];
      acc[nf] = __builtin_amdgcn_mfma_f32_16x16x32_bf16(a, bfr, acc[nf], 0, 0, 0);
    }
  }

  const float scale = (mat == 0) ? 0.125f : 1.0f;
  unsigned short* dst = (mat == 0 ? q_b : mat == 1 ? k_b : v_b);
  const int b = tok0 >> 10;
  const int tl0 = tok0 & 1023;
  unsigned short* dp = dst + (size_t)(b * NH + h) * NTOK * DHD;
#pragma unroll
  for (int nf = 0; nf < 4; ++nf)
#pragma unroll
    for (int r = 0; r < 4; ++r)
      dp[(size_t)(tl0 + lg * 4 + r) * DHD + nf * 16 + lq] = f2bf(acc[nf][r] * scale);
}

// ---------------- AdaIN stats (partial sums + atomics) ----------------
__global__ __launch_bounds__(256) void adain_stats_kernel(
    const unsigned short* __restrict__ k_b, const unsigned short* __restrict__ v_b,
    const float* __restrict__ m_ws, float* __restrict__ stats)
{
  const int bid = blockIdx.x;             // 256 blocks
  const int h = bid & 7, arr = (bid >> 3) & 1, ch = bid >> 4;   // 16 chunks of 64 toks
  const unsigned short* base = (arr ? v_b : k_b);
  const unsigned short* refp = base + (size_t)h * 65536;
  const unsigned short* fep  = base + (size_t)(8 + h) * 65536;
  const int t = threadIdx.x, dh = t & 63, ig = t >> 6;

  float rs = 0.f, rq = 0.f, fs = 0.f, fq = 0.f;
  for (int i = 0; i < 16; ++i) {
    const int tok = ch * 64 + ig * 16 + i;
    const float rv = bf2f(refp[(size_t)tok * DHD + dh]);
    rs += rv; rq += rv * rv;
    const float fv = bf2f(fep[(size_t)tok * DHD + dh]);
    const float mm = m_ws[tok];
    fs += mm * fv; fq += mm * fv * fv;
  }
  __shared__ float red[4][256];
  red[0][t] = rs; red[1][t] = rq; red[2][t] = fs; red[3][t] = fq;
  __syncthreads();
  if (ig == 0) {
    rs = red[0][dh] + red[0][dh + 64] + red[0][dh + 128] + red[0][dh + 192];
    rq = red[1][dh] + red[1][dh + 64] + red[1][dh + 128] + red[1][dh + 192];
    fs = red[2][dh] + red[2][dh + 64] + red[2][dh + 128] + red[2][dh + 192];
    fq = red[3][dh] + red[3][dh + 64] + red[3][dh + 128] + red[3][dh + 192];
    float* sp = stats + (size_t)(arr * 8 + h) * 256 + dh;
    atomicAdd(&sp[0], rs); atomicAdd(&sp[64], rq);
    atomicAdd(&sp[128], fs); atomicAdd(&sp[192], fq);
  }
}

// ---------------- AdaIN apply ----------------
__global__ __launch_bounds__(256) void adain_apply_kernel(
    unsigned short* __restrict__ k_b, unsigned short* __restrict__ v_b,
    const float* __restrict__ m_ws, const float* __restrict__ cnt_ws,
    const float* __restrict__ stats)
{
  const int bid = blockIdx.x;
  const int h = bid & 7, arr = (bid >> 3) & 1, ch = bid >> 4;
  unsigned short* fep = (arr ? v_b : k_b) + (size_t)(8 + h) * 65536;
  const int t = threadIdx.x, dh = t & 63, ig = t >> 6;

  const float* sp = stats + (size_t)(arr * 8 + h) * 256 + dh;
  const float rs = sp[0], rq = sp[64], fs = sp[128], fq = sp[192];
  const float cnt = cnt_ws[0];
  const float rmean = rs * (1.0f / 1024.0f);
  const float rstd = sqrtf(fmaxf((rq - 1024.0f * rmean * rmean) * (1.0f / 1023.0f), 0.f));
  const float fmean = fs / cnt;
  const float fstd = sqrtf(fmaxf((fq - cnt * fmean * fmean) / (cnt - 1.0f), 0.f));
  const float a = rstd / fstd;
  const float bb = rmean - fmean * a;

  for (int i = 0; i < 16; ++i) {
    const int tok = ch * 64 + ig * 16 + i;
    if (m_ws[tok] != 0.f) {
      const float fv = bf2f(fep[(size_t)tok * DHD + dh]);
      fep[(size_t)tok * DHD + dh] = f2bf(fv * a + bb);
    }
  }
}

// ---------------- V transpose: v_b [bh][tok][dh] -> v_bT [bh][dh][tok] ----------------
__global__ __launch_bounds__(256) void vtrans_kernel(const unsigned short* __restrict__ v_b,
                                                     unsigned short* __restrict__ v_bT)
{
  const int bh = blockIdx.y;
  const int tc = blockIdx.x;      // 16 chunks of 64 toks
  __shared__ unsigned short T[64][72];
  const int t = threadIdx.x;
  {
    const int tok = t >> 2, d0 = (t & 3) * 16;
    const unsigned short* src = v_b + ((size_t)bh * NTOK + tc * 64 + tok) * DHD + d0;
    ushort4 a0 = *(const ushort4*)&src[0];
    ushort4 a1 = *(const ushort4*)&src[4];
    ushort4 a2 = *(const ushort4*)&src[8];
    ushort4 a3 = *(const ushort4*)&src[12];
    T[d0 + 0][tok] = a0.x; T[d0 + 1][tok] = a0.y; T[d0 + 2][tok] = a0.z; T[d0 + 3][tok] = a0.w;
    T[d0 + 4][tok] = a1.x; T[d0 + 5][tok] = a1.y; T[d0 + 6][tok] = a1.z; T[d0 + 7][tok] = a1.w;
    T[d0 + 8][tok] = a2.x; T[d0 + 9][tok] = a2.y; T[d0 +10][tok] = a2.z; T[d0 +11][tok] = a2.w;
    T[d0 +12][tok] = a3.x; T[d0 +13][tok] = a3.y; T[d0 +14][tok] = a3.z; T[d0 +15][tok] = a3.w;
  }
  __syncthreads();
  {
    const int dh = t >> 2, t0 = (t & 3) * 16;
    unsigned short* dst = v_bT + ((size_t)bh * DHD + dh) * NTOK + tc * 64 + t0;
    s16x8 r0 = *(const s16x8*)&T[dh][t0];
    s16x8 r1 = *(const s16x8*)&T[dh][t0 + 8];
    *(s16x8*)&dst[0] = r0;
    *(s16x8*)&dst[8] = r1;
  }
}

// ---------------- flash attention (MFMA, swapped QK^T) ----------------
__global__ __launch_bounds__(64) void attn_mfma_kernel(
    const unsigned short* __restrict__ q_b, const unsigned short* __restrict__ k_b,
    const unsigned short* __restrict__ v_bT, const float* __restrict__ m_ws,
    unsigned short* __restrict__ o_b)
{
  const int bh = blockIdx.y, b = bh >> 3, h = bh & 7;
  const int q0 = blockIdx.x * 16;
  const int l = threadIdx.x, lq = l & 15, lg = l >> 4;

  __shared__ unsigned int P_u[16][36];   // row stride 144B -> uniform banks

  const unsigned short* qrow = q_b + ((size_t)bh * NTOK + q0 + lq) * DHD + lg * 8;
  s16x8 qf0 = *(const s16x8*)&qrow[0];
  s16x8 qf1 = *(const s16x8*)&qrow[32];

  const float mneg = (b == 1) ? (1.0f - m_ws[q0 + lq]) * (-1e9f) : 0.0f;

  float mrow = -1e30f, lrow = 0.f;
  f32x4 oacc[4] = {};

  const size_t own = (size_t)bh * 65536, ref = (size_t)h * 65536;

  for (int kt = 0; kt < 32; ++kt) {
    const size_t kb = (kt < 16 ? own : ref);
    const int tb = (kt & 15) * 64;
    const unsigned short* kp = k_b + kb + (size_t)tb * DHD;
    const unsigned short* vp = v_bT + kb + tb;

    // S^T = K · Q^T  (rows: kv, cols: q)
    f32x4 sf[4];
#pragma unroll
    for (int mf = 0; mf < 4; ++mf) {
      s16x8 a0 = *(const s16x8*)&kp[(size_t)(mf * 16 + lq) * DHD + lg * 8];
      s16x8 a1 = *(const s16x8*)&kp[(size_t)(mf * 16 + lq) * DHD + 32 + lg * 8];
      f32x4 z = {};
      z = __builtin_amdgcn_mfma_f32_16x16x32_bf16(a0, qf0, z, 0, 0, 0);
      sf[mf] = __builtin_amdgcn_mfma_f32_16x16x32_bf16(a1, qf1, z, 0, 0, 0);
    }

    const float add = (kt >= 16) ? mneg : 0.0f;
    float tm = -1e30f;
#pragma unroll
    for (int mf = 0; mf < 4; ++mf)
#pragma unroll
      for (int r = 0; r < 4; ++r) { sf[mf][r] += add; tm = fmaxf(tm, sf[mf][r]); }
    tm = fmaxf(tm, __shfl_xor(tm, 16));
    tm = fmaxf(tm, __shfl_xor(tm, 32));
    const float mnew = fmaxf(mrow, tm);
    const float alpha = __expf(mrow - mnew);
    mrow = mnew;

    float p[4][4];
    float ps = 0.f;
#pragma unroll
    for (int mf = 0; mf < 4; ++mf)
#pragma unroll
      for (int r = 0; r < 4; ++r) { const float e = __expf(sf[mf][r] - mnew); p[mf][r] = e; ps += e; }
    ps += __shfl_xor(ps, 16);
    ps += __shfl_xor(ps, 32);
    lrow = lrow * alpha + ps;

    float ar[4];
#pragma unroll
    for (int r = 0; r < 4; ++r) ar[r] = __shfl(alpha, lg * 4 + r, 16);
#pragma unroll
    for (int nf = 0; nf < 4; ++nf)
#pragma unroll
      for (int r = 0; r < 4; ++r) oacc[nf][r] *= ar[r];

    // pack P (bf16) into LDS: row lq, kv_local = 16*mf + 4*lg + r
#pragma unroll
    for (int mf = 0; mf < 4; ++mf) {
      uint2 wv;
      wv.x = (unsigned)f2bf(p[mf][0]) | ((unsigned)f2bf(p[mf][1]) << 16);
      wv.y = (unsigned)f2bf(p[mf][2]) | ((unsigned)f2bf(p[mf][3]) << 16);
      *(uint2*)&P_u[lq][8 * mf + 2 * lg] = wv;
    }

    // O += P · V
#pragma unroll
    for (int ks = 0; ks < 2; ++ks) {
      s16x8 pa = *(const s16x8*)&P_u[lq][16 * ks + 4 * lg];
#pragma unroll
      for (int nf = 0; nf < 4; ++nf) {
        s16x8 vb = *(const s16x8*)&vp[(size_t)(nf * 16 + lq) * NTOK + ks * 32 + lg * 8];
        oacc[nf] = __builtin_amdgcn_mfma_f32_16x16x32_bf16(pa, vb, oacc[nf], 0, 0, 0);
      }
    }
  }

  float rinv[4];
#pragma unroll
  for (int r = 0; r < 4; ++r) rinv[r] = 1.0f / __shfl(lrow, lg * 4 + r, 16);
  unsigned short* op = o_b + ((size_t)bh * NTOK + q0) * DHD;
#pragma unroll
  for (int nf = 0; nf < 4; ++nf)
#pragma unroll
    for (int r = 0; r < 4; ++r)
      op[(size_t)(lg * 4 + r) * DHD + nf * 16 + lq] = f2bf(oacc[nf][r] * rinv[r]);
}

// ---------------- output projection (MFMA) + bias, fp32 out ----------------
__global__ __launch_bounds__(256) void outproj_mfma_kernel(
    const unsigned short* __restrict__ o_b, const unsigned short* __restrict__ Wo_b,
    const float* __restrict__ bo, float* __restrict__ out)
{
  const int w = threadIdx.x >> 6, l = threadIdx.x & 63;
  const int lq = l & 15, lg = l >> 4;
  const int tile = blockIdx.x * 4 + w;          // 0..127
  const int c0 = blockIdx.y * 64;
  const int tok = tile * 16 + lq;
  const int b = tok >> 10, tl = tok & 1023;

  f32x4 acc[4] = {};
  for (int kt = 0; kt < 16; ++kt) {
    const int k0 = kt * 32 + lg * 8;
    const int hh = k0 >> 6, dd = k0 & 63;
    s16x8 a = *(const s16x8*)&o_b[((size_t)(b * NH + hh) * NTOK + tl) * DHD + dd];
#pragma unroll
    for (int nf = 0; nf < 4; ++nf) {
      s16x8 bfr = *(const s16x8*)&Wo_b[(size_t)(c0 + nf * 16 + lq) * QDIM + k0];
      acc[nf] = __builtin_amdgcn_mfma_f32_16x16x32_bf16(a, bfr, acc[nf], 0, 0, 0);
    }
  }
  const int row0 = tile * 16;
#pragma unroll
  for (int nf = 0; nf < 4; ++nf) {
    const float bv = bo[c0 + nf * 16 + lq];
#pragma unroll
    for (int r = 0; r < 4; ++r)
      out[(size_t)(row0 + lg * 4 + r) * QDIM + c0 + nf * 16 + lq] = acc[nf][r] + bv;
  }
}

extern "C" void kernel_launch(void* const* d_in, const int* in_sizes, int n_in,
                              void* d_out, int out_size, void* d_ws, size_t ws_size,
                              hipStream_t stream) {
  const float* x    = (const float*)d_in[0];
  const float* mask = (const float*)d_in[1];
  const float* Wq   = (const float*)d_in[2];
  const float* Wk   = (const float*)d_in[3];
  const float* Wv   = (const float*)d_in[4];
  const float* Wo   = (const float*)d_in[5];
  const float* bo   = (const float*)d_in[6];
  float* out = (float*)d_out;

  char* ws = (char*)d_ws;
  unsigned short* x_b  = (unsigned short*)ws;                    // 2,097,152 B
  unsigned short* w_b  = (unsigned short*)(ws + 2097152);        // Wq,Wk,Wv,Wo contiguous: 2,097,152 B
  unsigned short* Wo_b = (unsigned short*)(ws + 2097152 + 3 * 524288);
  unsigned short* q_b  = (unsigned short*)(ws + 4194304);
  unsigned short* k_b  = (unsigned short*)(ws + 6291456);
  unsigned short* v_b  = (unsigned short*)(ws + 8388608);
  unsigned short* v_bT = (unsigned short*)(ws + 10485760);
  unsigned short* o_b  = (unsigned short*)(ws + 12582912);
  float* m_ws   = (float*)(ws + 14680064);
  float* cnt_ws = (float*)(ws + 14684160);
  float* stats  = (float*)(ws + 14684416);                       // 16*256 f32 = 16 KiB

  hipMemsetAsync(stats, 0, 16 * 256 * sizeof(float), stream);
  cast_kernel<<<2048, 256, 0, stream>>>(x, Wq, Wk, Wv, Wo, x_b);
  mask_cnt_kernel<<<1, 1024, 0, stream>>>(mask, m_ws, cnt_ws);
  proj_mfma_kernel<<<dim3(32, 24), 256, 0, stream>>>(x_b, w_b, q_b, k_b, v_b);
  adain_stats_kernel<<<256, 256, 0, stream>>>(k_b, v_b, m_ws, stats);
  adain_apply_kernel<<<256, 256, 0, stream>>>(k_b, v_b, m_ws, cnt_ws, stats);
  vtrans_kernel<<<dim3(16, 16), 256, 0, stream>>>(v_b, v_bT);
  attn_mfma_kernel<<<dim3(64, 16), 64, 0, stream>>>(q_b, k_b, v_bT, m_ws, o_b);
  outproj_mfma_kernel<<<dim3(32, 8), 256, 0, stream>>>(o_b, Wo_b, bo, out);
}